// Round 12
// baseline (195.220 us; speedup 1.0000x reference)
//
#include <hip/hip_runtime.h>

// NCC loss, fused single pass. Layout [n][1][d][h][w], n=2, d=160, h=192, w=192, f32.
// R17: NO LDS. Load windows directly from global (L1/L2/L3-cached).
//   Evidence: R5-R16 pin per-wave step wall at 3800-5400 cyc vs ~1300 issue-cyc,
//   resident waves ~5-8/CU regardless of every scheduling/residency lever tried
//   (-33% LDS reads R6, counted vmcnt R9, no barriers R11, row pipeline R12, 8-wave
//   R13, CD=16 R14 [the only win, work cut], 1-round grid R15, 2880 blocks R16).
//   The one preserved structure: the LDS staging skeleton {global_load_lds DMA ->
//   ds_read_b128 -> vmcnt/lgkmcnt(0) drains} every step. But total input = 94 MB
//   fits L3 (256MB) entirely; FETCH 115-184MB shows L2/L3 already absorb halo
//   re-reads; within a step the 5-row H-overlap sits in L1 (wave window ~4.5KB
//   << 32KB). Guide common-mistake #7 (m169, +26%): don't LDS-stage what caches.
//   Change: per row per array, 3 ALIGNED float4 loads (R5's 12-float window,
//   cols w0-4..w0+7, consume [2..9]) straight from global. Addresses: uniform
//   slice base (SGPR) + precomputed per-lane offsets rcI[5][3] -> zero per-load
//   VALU addressing. W-edge: per-seg clamp + zero a[2],a[3] / a[8],a[9] (zl/zr,
//   exactly R5's semantics). H-edge (2/48 wave-positions): guarded slow path.
//   Drops: tile[], DMA, asm waitcnts, double-buffer, prologue, bank conflicts.
//   Config = R14's best: CD=16, 720 blocks (3x12x20), 4 waves. Single variable.
//   Signatures predicted: SQ_LDS_BANK_CONFLICT -> ~0, LDS_Block_Size minimal,
//   VGPR ~180-200 (WRITE_SIZE must stay ~KB: spill watch).
// R14 (kept): CD=16 (T=20=4x5 phases, 160=10x16): slice-processings 200 vs 267.
// R6-equivalent windowing; R5's zl/zr edge zeroing; D-OOB slices contribute
//   zeroed ring entries (box_sum zero-pads in D); ring in registers; no
//   launch_bounds min-waves arg (R3/R10: spills the ring -> ~1GB scratch).

namespace {
constexpr int Wd = 192, Hd = 192, Dd = 160;
constexpr int SH = 192;              // h stride (floats)
constexpr int SD = 192 * 192;        // d stride
constexpr long SN = (long)SD * Dd;   // n stride
constexpr int CD = 16;               // d outputs per chunk; T = CD+4 = 20
constexpr int NCHUNK = 10;           // 160/16 exact
constexpr float INV_V = 1.0f / 125.0f;
constexpr float EPSf = 1e-5f;

__device__ __forceinline__ void wslide(const float h[8], float o[4]) {
  float s0 = h[0] + h[1] + h[2] + h[3] + h[4];
  float s1 = s0 - h[0] + h[5];
  float s2 = s1 - h[1] + h[6];
  float s3 = s2 - h[2] + h[7];
  o[0] = s0; o[1] = s1; o[2] = s2; o[3] = s3;
}
} // namespace

__global__ __launch_bounds__(256) void ncc_fused(const float* __restrict__ I,
                                                 const float* __restrict__ Jv,
                                                 float* __restrict__ out) {
  __shared__ float red[4];

  const int tid  = threadIdx.x;
  const int lane = tid & 63, wave = tid >> 6;
  const int tx   = lane & 15;       // w-run index (4 outputs each)
  const int tyw  = lane >> 4;       // output row within wave's 4-row strip
  const int wbase = blockIdx.x * 64;
  const int hbase = blockIdx.y * 16;          // 16-tall H tile (4 waves x 4 rows)
  const int n   = blockIdx.z / NCHUNK;
  const int d_lo = (blockIdx.z % NCHUNK) * CD;
  const int hw0 = hbase + 4 * wave - 2;   // window row r <-> global h = hw0 + r
  const bool interior = (hw0 >= 0) && (hw0 + 7 < Hd);  // 46/48 wave-positions

  const float* Ib = I  + (long)n * SN;
  const float* Jb = Jv + (long)n * SN;

  // ---- per-thread column window: cols w0-4 .. w0+7 as 3 aligned 16B segs ----
  const int w0 = wbase + 4 * tx;
  const int c0 = max(w0 - 4, 0);          // clamped only at (bx0, tx0)
  const int c1 = w0;                      // always in [0, 188]
  const int c2 = min(w0 + 8, Wd - 4);     // clamped only at (bx2, tx15)
  // Clamp-shifted segs only feed a[2],a[3] (cols -2,-1) / a[8],a[9] (cols 192,193):
  const bool zl = (wbase == 0)   && (tx == 0);
  const bool zr = (wbase == 128) && (tx == 15);

  // ---- per-row float offsets within a slice (fixed across steps) ----
  int rcI[5][3]; bool rowok[5];
  #pragma unroll
  for (int dh = 0; dh < 5; ++dh) {
    const int hh = hw0 + tyw + dh;
    rowok[dh] = (hh >= 0) && (hh < Hd);
    const int ro = min(max(hh, 0), Hd - 1) * SH;
    rcI[dh][0] = ro + c0; rcI[dh][1] = ro + c1; rcI[dh][2] = ro + c2;
  }

  float ring[5][5][4];  // [phase][channel:{I,J,II,JJ,IJ}][k]
  float acc = 0.0f;

  constexpr int T = CD + 4; // 20 steps; output d = d_lo + t - 4 for t>=4
  for (int t0 = 0; t0 < T; t0 += 5) {
    #pragma unroll
    for (int p = 0; p < 5; ++p) {             // phase = t % 5 (compile-time)
      const int t = t0 + p;
      const int s = d_lo - 2 + t;             // slice for this step

      float hsI[8], hsJ[8], hsII[8], hsJJ[8], hsIJ[8];
      if (s >= 0 && s < Dd) {
        const float* pI = Ib + (long)s * SD;  // uniform slice bases (SGPR)
        const float* pJ = Jb + (long)s * SD;
        if (interior) {
          // ---- row 0 initializes (saves the 40 zero-init movs) ----
          {
            const int* rc = rcI[0];
            float a[12], b[12];
            ((float4*)a)[0] = *(const float4*)(pI + rc[0]);
            ((float4*)a)[1] = *(const float4*)(pI + rc[1]);
            ((float4*)a)[2] = *(const float4*)(pI + rc[2]);
            ((float4*)b)[0] = *(const float4*)(pJ + rc[0]);
            ((float4*)b)[1] = *(const float4*)(pJ + rc[1]);
            ((float4*)b)[2] = *(const float4*)(pJ + rc[2]);
            if (zl) { a[2]=0.f; a[3]=0.f; b[2]=0.f; b[3]=0.f; }
            if (zr) { a[8]=0.f; a[9]=0.f; b[8]=0.f; b[9]=0.f; }
            #pragma unroll
            for (int c = 0; c < 8; ++c) {
              const float x = a[c + 2], y = b[c + 2];
              hsI[c] = x; hsJ[c] = y;
              hsII[c] = x * x; hsJJ[c] = y * y; hsIJ[c] = x * y;
            }
          }
          #pragma unroll
          for (int dh = 1; dh < 5; ++dh) {
            const int* rc = rcI[dh];
            float a[12], b[12];
            ((float4*)a)[0] = *(const float4*)(pI + rc[0]);
            ((float4*)a)[1] = *(const float4*)(pI + rc[1]);
            ((float4*)a)[2] = *(const float4*)(pI + rc[2]);
            ((float4*)b)[0] = *(const float4*)(pJ + rc[0]);
            ((float4*)b)[1] = *(const float4*)(pJ + rc[1]);
            ((float4*)b)[2] = *(const float4*)(pJ + rc[2]);
            if (zl) { a[2]=0.f; a[3]=0.f; b[2]=0.f; b[3]=0.f; }
            if (zr) { a[8]=0.f; a[9]=0.f; b[8]=0.f; b[9]=0.f; }
            #pragma unroll
            for (int c = 0; c < 8; ++c) {
              const float x = a[c + 2], y = b[c + 2];
              hsI[c]  += x;
              hsJ[c]  += y;
              hsII[c] = fmaf(x, x, hsII[c]);
              hsJJ[c] = fmaf(y, y, hsJJ[c]);
              hsIJ[c] = fmaf(x, y, hsIJ[c]);
            }
          }
        } else {
          // ---- slow path (2 H-edge wave-positions): guarded rows ----
          #pragma unroll
          for (int c = 0; c < 8; ++c) {
            hsI[c] = 0.f; hsJ[c] = 0.f; hsII[c] = 0.f; hsJJ[c] = 0.f; hsIJ[c] = 0.f;
          }
          #pragma unroll
          for (int dh = 0; dh < 5; ++dh) {
            if (rowok[dh]) {
              const int* rc = rcI[dh];
              float a[12], b[12];
              ((float4*)a)[0] = *(const float4*)(pI + rc[0]);
              ((float4*)a)[1] = *(const float4*)(pI + rc[1]);
              ((float4*)a)[2] = *(const float4*)(pI + rc[2]);
              ((float4*)b)[0] = *(const float4*)(pJ + rc[0]);
              ((float4*)b)[1] = *(const float4*)(pJ + rc[1]);
              ((float4*)b)[2] = *(const float4*)(pJ + rc[2]);
              if (zl) { a[2]=0.f; a[3]=0.f; b[2]=0.f; b[3]=0.f; }
              if (zr) { a[8]=0.f; a[9]=0.f; b[8]=0.f; b[9]=0.f; }
              #pragma unroll
              for (int c = 0; c < 8; ++c) {
                const float x = a[c + 2], y = b[c + 2];
                hsI[c]  += x;
                hsJ[c]  += y;
                hsII[c] = fmaf(x, x, hsII[c]);
                hsJJ[c] = fmaf(y, y, hsJJ[c]);
                hsIJ[c] = fmaf(x, y, hsIJ[c]);
              }
            }
          }
        }
      } else {
        // D-OOB slice: contributes zeros to the ring (box_sum zero-pads in D)
        #pragma unroll
        for (int c = 0; c < 8; ++c) {
          hsI[c] = 0.f; hsJ[c] = 0.f; hsII[c] = 0.f; hsJJ[c] = 0.f; hsIJ[c] = 0.f;
        }
      }

      // ---- W-window sliding sums -> ring ----
      wslide(hsI,  ring[p][0]);
      wslide(hsJ,  ring[p][1]);
      wslide(hsII, ring[p][2]);
      wslide(hsJJ, ring[p][3]);
      wslide(hsIJ, ring[p][4]);

      // ---- D-window + cc ----
      const int d = d_lo + t - 4;
      if (t >= 4 && d < Dd) {
        #pragma unroll
        for (int k = 0; k < 4; ++k) {
          float SI = 0.f, SJ = 0.f, SII = 0.f, SJJ = 0.f, SIJ = 0.f;
          #pragma unroll
          for (int q = 0; q < 5; ++q) {
            SI  += ring[q][0][k];
            SJ  += ring[q][1][k];
            SII += ring[q][2][k];
            SJJ += ring[q][3][k];
            SIJ += ring[q][4][k];
          }
          const float cross = SIJ - SI * SJ * INV_V;
          const float vI    = SII - SI * SI * INV_V;
          const float vJ    = SJJ - SJ * SJ * INV_V;
          acc += cross * cross / (vI * vJ + EPSf);
        }
      }
    }
  }

  // ---- block reduction -> single atomic per block ----
  #pragma unroll
  for (int off = 32; off > 0; off >>= 1) acc += __shfl_xor(acc, off, 64);
  if (lane == 0) red[wave] = acc;
  __syncthreads();
  if (tid == 0) {
    const float total = red[0] + red[1] + red[2] + red[3];
    atomicAdd(out, total * (-1.0f / 11796480.0f)); // -mean over 2*160*192*192
  }
}

extern "C" void kernel_launch(void* const* d_in, const int* in_sizes, int n_in,
                              void* d_out, int out_size, void* d_ws, size_t ws_size,
                              hipStream_t stream) {
  const float* I = (const float*)d_in[0];
  const float* J = (const float*)d_in[1];
  float* out = (float*)d_out;
  hipMemsetAsync(out, 0, sizeof(float), stream);
  dim3 grid(3, 12, 2 * NCHUNK); // W tiles * H tiles(16) * (n x 10 d-chunks of 16)
  ncc_fused<<<grid, 256, 0, stream>>>(I, J, out);
}

// Round 13
// 160.467 us; speedup vs baseline: 1.2166x; 1.2166x over previous
//
#include <hip/hip_runtime.h>

// NCC loss, fused single pass. Layout [n][1][d][h][w], n=2, d=160, h=192, w=192, f32.
// R18: distance-2 private prefetch with counted vmcnt(5) on the R14 structure.
//   R17 (no LDS, direct global loads) regressed 74->116us with conflicts=0 and no
//   spill: exposed L2/L3 latency per step at ~5 resident waves/CU. So staging is
//   load-bearing and the stall is per-step EXPOSED LATENCY, not pipe saturation.
//   R14 (best, 74us) drains its own 5 DMAs with vmcnt(0) issued only ~1000 cycles
//   earlier -- L3-hit latency (~500-700cy) + queueing barely covered; inferred step
//   wall ~4400cy vs ~1000 issue-cycles. Fix: 3-buffer private ring, prefetch s+2:
//     step t: read buf[bc] (slice s=d_lo-2+t); issue 5 DMAs slice d_lo+t (=s+2)
//             into buf[(bc+2)%3]; end: s_waitcnt vmcnt(5) lgkmcnt(0)
//   -> drains step t-1's 5 (oldest-first, m135), leaves own 5 in flight with TWO
//   compute phases to land. Non-issuing steps (t>=T-2 or d_lo+t>=Dd, wave-uniform)
//   wait vmcnt(0), keeping the oldest-first count exact at tails. Prologue stages
//   d_lo-2 AND d_lo-1, drains vmcnt(0) fully (R9 lesson: order-independent start).
//   WAR (DMA at step t overwrites the buffer read at step t-1): closed by the
//   lgkmcnt(0) in every end-of-step wait. LDS 4 waves x 3 x 4608B = 55.3KB.
// R14 (kept): CD=16 (T=20=4x5 phases, 160=10x16): slice-processings 200 vs 267.
// R11 (kept): barrier-free wave-private structure; per-lane array select via
//   global-address offset (m104/m108: only the LDS dest is lane-linear); no
//   s_barrier in the D-loop; one __syncthreads before the final reduction.
// R6 (kept): aligned layout col c <-> w = wbase-2+c, 2x aligned ds_read_b128 per
//   row/array; W-edge clamp-shift fixed by in-register permute (fixl/fixr).
// R5 (kept): all lanes always issue DMA with CLAMPED global addrs; tail mask
//   (r=4: lane<32) keeps lane 0 active. H-OOB rows skipped in compute, D-OOB
//   slices skipped wave-uniformly, ring in registers, NO occupancy clamp
//   (R3/R10: a min-waves arg spills the ring -> ~1GB scratch traffic).

namespace {
constexpr int Wd = 192, Hd = 192, Dd = 160;
constexpr int SH = 192;              // h stride (floats)
constexpr int SD = 192 * 192;        // d stride
constexpr long SN = (long)SD * Dd;   // n stride
constexpr int CD = 16;               // d outputs per chunk; T = CD+4 = 20
constexpr int NCHUNK = 10;           // 160/16 exact
constexpr int TROW = 72;             // floats per row (18 16B-segs)
constexpr int ARRF = 8 * TROW;       // 576 floats: one array's 8-row block
constexpr int BUFF = 2 * ARRF;       // 1152 floats: one slice buffer (I+J)
constexpr int WREGF = 3 * BUFF;      // 3456 floats: one wave's region (3 buffers)
constexpr int NW = 4;                // waves per block
constexpr float INV_V = 1.0f / 125.0f;
constexpr float EPSf = 1e-5f;

__device__ __forceinline__ void wslide(const float h[8], float o[4]) {
  float s0 = h[0] + h[1] + h[2] + h[3] + h[4];
  float s1 = s0 - h[0] + h[5];
  float s2 = s1 - h[1] + h[6];
  float s3 = s2 - h[2] + h[7];
  o[0] = s0; o[1] = s1; o[2] = s2; o[3] = s3;
}

__device__ __forceinline__ void gl_lds16(const float* g, float* l) {
  __builtin_amdgcn_global_load_lds(
      (const __attribute__((address_space(1))) void*)g,
      (__attribute__((address_space(3))) void*)l, 16, 0, 0);
}
} // namespace

__global__ __launch_bounds__(256) void ncc_fused(const float* __restrict__ I,
                                                 const float* __restrict__ Jv,
                                                 float* __restrict__ out) {
  __shared__ float tile[NW * WREGF];  // 4 waves x 13,824 B = 55,296 B
  __shared__ float red[NW];

  const int tid  = threadIdx.x;
  const int lane = tid & 63, wave = tid >> 6;
  const int tx   = lane & 15;       // w-run index (4 outputs each)
  const int tyw  = lane >> 4;       // output row within wave's 4-row strip
  const int wbase = blockIdx.x * 64;
  const int hbase = blockIdx.y * 16;          // 16-tall H tile (4 waves x 4 rows)
  const int n   = blockIdx.z / NCHUNK;
  const int d_lo = (blockIdx.z % NCHUNK) * CD;
  const int hw0 = hbase + 4 * wave - 2;   // region row r <-> global h = hw0 + r

  const float* Ib = I  + (long)n * SN;
  const float* Jb = Jv + (long)n * SN;
  const long  dJ  = (long)(Jb - Ib);      // per-lane array select as an offset

  // ---- wave-private staging descriptors: 288 16B-segs over 5 issues/lane ----
  // seg = r*64+lane; arr = seg>=144; rem = seg - arr*144; row = rem/18; c16 = rem%18
  // LDS float offset within buffer = seg*4 (lane-linear per issue: base + lane*16B)
  long goffL[5]; int lloc[5]; bool on[5];
  #pragma unroll
  for (int r = 0; r < 5; ++r) {
    const int seg = r * 64 + lane;
    on[r] = (r < 4) || (lane < 32);              // 288 = 4*64 + 32 (lane 0 active)
    const int arr = (seg >= 144) ? 1 : 0;
    const int rem = seg - arr * 144;
    const int row = rem / 18, c16 = rem % 18;
    const int hh = hw0 + row;
    const int hc = min(max(hh, 0), Hd - 1);      // CLAMP, never mask
    const int gw = wbase - 2 + c16 * 4;
    const int gc = min(max(gw, 0), Wd - 4);
    goffL[r] = (arr ? dJ : 0L) + (long)(hc * SH + gc);
    lloc[r]  = seg * 4;                          // float offset
  }
  float* wreg = &tile[wave * WREGF];

  // ---- prologue: stage d_lo-2 -> buf0 AND d_lo-1 -> buf1, drain FULLY ----
  // Both in-range iff d_lo > 0 (d_lo multiple of 16, max 144 -> 143 < Dd).
  if (d_lo > 0) {
    const float* b0 = Ib + (long)(d_lo - 2) * SD;
    const float* b1 = Ib + (long)(d_lo - 1) * SD;
    #pragma unroll
    for (int r = 0; r < 5; ++r) if (on[r]) gl_lds16(b0 + goffL[r], wreg + lloc[r]);
    #pragma unroll
    for (int r = 0; r < 5; ++r) if (on[r]) gl_lds16(b1 + goffL[r], wreg + BUFF + lloc[r]);
  }
  asm volatile("s_waitcnt vmcnt(0) lgkmcnt(0)" ::: "memory"); // order-independent start

  // W-edge fixups (layout col c <-> w = wbase-2+c): clamp-shifted segs only touch
  // these 2 thread-columns; true values live in other slots of the same read.
  const bool fixl = (wbase == 0)   && (tx == 0);
  const bool fixr = (wbase == 128) && (tx == 15);

  float ring[5][5][4];  // [phase][channel:{I,J,II,JJ,IJ}][k]
  float acc = 0.0f;

  int bc = 0;  // runtime ring index: buffer holding slice d_lo-2+t (= t%3)
  constexpr int T = CD + 4; // 20 steps; output d = d_lo + t - 4 for t>=4
  for (int t0 = 0; t0 < T; t0 += 5) {
    #pragma unroll
    for (int p = 0; p < 5; ++p) {             // phase = t % 5 (compile-time)
      const int t = t0 + p;
      const int s = d_lo - 2 + t;             // slice in buf[bc]

      // ---- distance-2 prefetch: slice d_lo+t (= s+2) -> buf[(bc+2)%3] ----
      const bool issue = ((t + 2) < T) && ((d_lo + t) < Dd);  // wave-uniform
      if (issue) {
        const float* base = Ib + (long)(d_lo + t) * SD;
        int bw = bc - 1; if (bw < 0) bw += 3;          // (bc+2)%3
        float* dst = wreg + bw * BUFF;
        #pragma unroll
        for (int r = 0; r < 5; ++r) if (on[r]) gl_lds16(base + goffL[r], dst + lloc[r]);
      }

      // ---- H-window accumulate from current private buffer ----
      float hsI[8], hsJ[8], hsII[8], hsJJ[8], hsIJ[8];
      #pragma unroll
      for (int c = 0; c < 8; ++c) {
        hsI[c] = 0.f; hsJ[c] = 0.f; hsII[c] = 0.f; hsJJ[c] = 0.f; hsIJ[c] = 0.f;
      }
      if (s >= 0 && s < Dd) {
        const float* bufc = wreg + bc * BUFF;
        #pragma unroll
        for (int dh = 0; dh < 5; ++dh) {
          const int rrow = tyw + dh;           // region rows tyw..tyw+4 (of 8)
          const int hh = hw0 + rrow;
          if (hh >= 0 && hh < Hd) {            // skip clamped-duplicate halo rows
            const float* pa = bufc + rrow * TROW + 4 * tx;  // cols 4tx..4tx+7, 16B-aligned
            const float* pb = pa + ARRF;       // J block
            float a[8], b[8];
            ((float4*)a)[0] = ((const float4*)pa)[0];
            ((float4*)a)[1] = ((const float4*)pa)[1];
            ((float4*)b)[0] = ((const float4*)pb)[0];
            ((float4*)b)[1] = ((const float4*)pb)[1];
            if (fixl) { a[2]=a[0]; a[3]=a[1]; a[0]=0.f; a[1]=0.f;
                        b[2]=b[0]; b[3]=b[1]; b[0]=0.f; b[1]=0.f; }
            if (fixr) { a[4]=a[6]; a[5]=a[7]; a[6]=0.f; a[7]=0.f;
                        b[4]=b[6]; b[5]=b[7]; b[6]=0.f; b[7]=0.f; }
            #pragma unroll
            for (int c = 0; c < 8; ++c) {
              const float x = a[c], y = b[c];  // cols w0-2..w0+5
              hsI[c]  += x;
              hsJ[c]  += y;
              hsII[c] = fmaf(x, x, hsII[c]);
              hsJJ[c] = fmaf(y, y, hsJJ[c]);
              hsIJ[c] = fmaf(x, y, hsIJ[c]);
            }
          }
        }
      }

      // ---- W-window sliding sums -> ring ----
      wslide(hsI,  ring[p][0]);
      wslide(hsJ,  ring[p][1]);
      wslide(hsII, ring[p][2]);
      wslide(hsJJ, ring[p][3]);
      wslide(hsIJ, ring[p][4]);

      // ---- D-window + cc ----
      const int d = d_lo + t - 4;
      if (t >= 4 && d < Dd) {
        #pragma unroll
        for (int k = 0; k < 4; ++k) {
          float SI = 0.f, SJ = 0.f, SII = 0.f, SJJ = 0.f, SIJ = 0.f;
          #pragma unroll
          for (int q = 0; q < 5; ++q) {
            SI  += ring[q][0][k];
            SJ  += ring[q][1][k];
            SII += ring[q][2][k];
            SJJ += ring[q][3][k];
            SIJ += ring[q][4][k];
          }
          const float cross = SIJ - SI * SJ * INV_V;
          const float vI    = SII - SI * SI * INV_V;
          const float vJ    = SJJ - SJ * SJ * INV_V;
          acc += cross * cross / (vI * vJ + EPSf);
        }
      }

      // ---- counted wait: drain step t-1's 5 DMAs, keep own 5 in flight ----
      if (issue) asm volatile("s_waitcnt vmcnt(5) lgkmcnt(0)" ::: "memory");
      else       asm volatile("s_waitcnt vmcnt(0) lgkmcnt(0)" ::: "memory");
      bc += 1; if (bc == 3) bc = 0;
    }
  }

  // ---- block reduction -> single atomic per block ----
  #pragma unroll
  for (int off = 32; off > 0; off >>= 1) acc += __shfl_xor(acc, off, 64);
  if (lane == 0) red[wave] = acc;
  __syncthreads();
  if (tid == 0) {
    const float total = red[0] + red[1] + red[2] + red[3];
    atomicAdd(out, total * (-1.0f / 11796480.0f)); // -mean over 2*160*192*192
  }
}

extern "C" void kernel_launch(void* const* d_in, const int* in_sizes, int n_in,
                              void* d_out, int out_size, void* d_ws, size_t ws_size,
                              hipStream_t stream) {
  const float* I = (const float*)d_in[0];
  const float* J = (const float*)d_in[1];
  float* out = (float*)d_out;
  hipMemsetAsync(out, 0, sizeof(float), stream);
  dim3 grid(3, 12, 2 * NCHUNK); // W tiles * H tiles(16) * (n x 10 d-chunks of 16)
  ncc_fused<<<grid, 256, 0, stream>>>(I, J, out);
}